// Round 15
// baseline (433.597 us; speedup 1.0000x reference)
//
#include <hip/hip_runtime.h>
#include <hip/hip_bf16.h>
#include <math.h>

#define SEQ 2048
#define NHEADS 32
#define NKVH 8
#define HD 128
#define HIDDEN 4096
#define NQKV 6144

typedef unsigned short u16;
typedef unsigned int u32;
typedef __attribute__((ext_vector_type(8))) __bf16 bf16x8;
typedef __attribute__((ext_vector_type(4))) float f32x4;
typedef __attribute__((ext_vector_type(4))) u16 u16x4;
typedef __attribute__((ext_vector_type(4))) u32 u32x4;

__device__ __forceinline__ u16 f2bf(float f) {
  u32 u = __builtin_bit_cast(u32, f);
  u32 r = (u + 0x7fffu + ((u >> 16) & 1u)) >> 16;
  return (u16)r;
}
__device__ __forceinline__ float bf2f(u16 h) {
  return __builtin_bit_cast(float, ((u32)h) << 16);
}
__device__ __forceinline__ void gload_lds16(const void* g, void* l) {
  __builtin_amdgcn_global_load_lds(
      (const __attribute__((address_space(1))) u32*)g,
      (__attribute__((address_space(3))) u32*)l, 16, 0, 0);
}

#define BAR __builtin_amdgcn_s_barrier()
#define PRIO1 __builtin_amdgcn_s_setprio(1)
#define PRIO0 __builtin_amdgcn_s_setprio(0)
#define VMW(n) asm volatile("s_waitcnt vmcnt(" #n ")" ::: "memory")

// ---------------- fused prep: X f32->bf16 + Wq/Wk/Wv transpose f32->bf16^T ----------------
__global__ void __launch_bounds__(256) prep_all(
    const float* __restrict__ hs, u16* __restrict__ Xb,
    const float* __restrict__ Wq, u16* __restrict__ Wqt,
    const float* __restrict__ Wk, u16* __restrict__ Wkt,
    const float* __restrict__ Wv, u16* __restrict__ Wvt) {
  const int bid = blockIdx.x;
  if (bid < 8192) {  // X conversion, 4 f32/thread
    const int i = (bid * 256 + threadIdx.x) * 4;
    const float4 v = *(const float4*)(hs + i);
    u16x4 o;
    o.x = f2bf(v.x); o.y = f2bf(v.y); o.z = f2bf(v.z); o.w = f2bf(v.w);
    *(u16x4*)(Xb + i) = o;
    return;
  }
  __shared__ float tile[64][65];
  const float* src; u16* dst; int C, lc, tb;
  const int b2 = bid - 8192;
  if (b2 < 4096) { src = Wq; dst = Wqt; C = 4096; lc = 6; tb = b2; }
  else if (b2 < 5120) { src = Wk; dst = Wkt; C = 1024; lc = 4; tb = b2 - 4096; }
  else { src = Wv; dst = Wvt; C = 1024; lc = 4; tb = b2 - 5120; }
  const int r0 = (tb >> lc) * 64, c0 = (tb & ((1 << lc) - 1)) * 64;
  const int tx = threadIdx.x & 63, ty = threadIdx.x >> 6;
#pragma unroll
  for (int j = 0; j < 16; ++j)
    tile[ty + j * 4][tx] = src[(size_t)(r0 + ty + j * 4) * C + c0 + tx];
  __syncthreads();
#pragma unroll
  for (int j = 0; j < 16; ++j)
    dst[(size_t)(c0 + ty + j * 4) * 4096 + r0 + tx] = f2bf(tile[tx][ty + j * 4]);
}

// ---------------- fused post-QKV: RoPE(q)+RoPE(k) + V transpose + Wo transpose ----------------
__global__ void __launch_bounds__(256) post_qkv(u16* __restrict__ qkv, u16* __restrict__ vtb,
                                                const int* __restrict__ pos,
                                                const float* __restrict__ Wsrc,
                                                u16* __restrict__ Wdst) {
  const int bid = blockIdx.x;
  if (bid < 20480) {  // RoPE
    int idx, hoff, sshift;
    float oscale;
    if (bid < 16384) {  // q: 32 heads at col 0
      idx = bid * 256 + threadIdx.x;
      hoff = ((idx >> 6) & 31) * 128;
      sshift = 11;
      oscale = 0.08838834764831845f * 1.44269504088896340f;  // 1/sqrt(128)*log2(e)
    } else {  // k: 8 heads at col 4096
      idx = (bid - 16384) * 256 + threadIdx.x;
      hoff = 4096 + ((idx >> 6) & 7) * 128;
      sshift = 9;
      oscale = 1.0f;
    }
    const int j = idx & 63;
    const int s = idx >> sshift;
    if (s >= SEQ) return;
    const float p = (float)pos[s];
    const float invf = __expf((float)j * -0.14391156831212787f);  // -ln(10000)/64
    const float ang = p * invf;
    const float c = cosf(ang), sn = sinf(ang);
    u16* bp = qkv + (size_t)s * NQKV + hoff + j;
    const float x1 = bf2f(bp[0]), x2 = bf2f(bp[64]);
    bp[0] = f2bf((x1 * c - x2 * sn) * oscale);
    bp[64] = f2bf((x2 * c + x1 * sn) * oscale);
    return;
  }
  if (bid < 22528) {
    // V transpose: qkv[:,5120:6144] ([2048][1024] strided) -> vtb [1024][2048]
    __shared__ u16 tile[32][34];
    const int b2 = bid - 20480;
    const int c0 = (b2 & 31) * 32, r0 = (b2 >> 5) * 32;
    const int tx = threadIdx.x & 31, ty = threadIdx.x >> 5;
#pragma unroll
    for (int i = 0; i < 4; ++i)
      tile[ty + i * 8][tx] = qkv[(size_t)(r0 + ty + i * 8) * NQKV + 5120 + c0 + tx];
    __syncthreads();
#pragma unroll
    for (int i = 0; i < 4; ++i)
      vtb[(size_t)(c0 + ty + i * 8) * 2048 + r0 + tx] = tile[tx][ty + i * 8];
    return;
  }
  // Wo transpose: f32 [4096][4096] -> bf16^T, one 64x64 tile per block (4096 blocks)
  __shared__ float tf[64][65];
  const int tb = bid - 22528;
  const int r0 = (tb >> 6) * 64, c0 = (tb & 63) * 64;
  const int tx = threadIdx.x & 63, ty = threadIdx.x >> 6;
#pragma unroll
  for (int j = 0; j < 16; ++j)
    tf[ty + j * 4][tx] = Wsrc[(size_t)(r0 + ty + j * 4) * 4096 + c0 + tx];
  __syncthreads();
#pragma unroll
  for (int j = 0; j < 16; ++j)
    Wdst[(size_t)(c0 + ty + j * 4) * 4096 + r0 + tx] = f2bf(tf[tx][ty + j * 4]);
}

// ================= QKV GEMM: BM=256, BN=192, BK=64, 256 blocks (full CU fill) =================
__global__ void __launch_bounds__(512) gemm_qkv(
    const u16* __restrict__ A, const u16* __restrict__ B, u16* __restrict__ C) {
  __shared__ u16 As[2][256 * 64];
  __shared__ u16 Bs[2][192 * 64];
  const int t = threadIdx.x;
  const int lane = t & 63, w = t >> 6;
  const int wr = w >> 2, wc = w & 3;
  const int l15 = lane & 15, l4 = lane >> 4;

  const int bid = blockIdx.x;
  const int xcd = bid & 7, ii = bid >> 3;
  const int byt = xcd, bxt = ii;
  const int row0 = byt * 256, col0 = bxt * 192;

  auto stageA_part = [&](int buf, int tile, int gfirst) {
#pragma unroll
    for (int gg = 0; gg < 2; ++gg) {
      const int g = gfirst + gg * 2;
      const int o = (g * 512 + t) * 16;
      const int ridx = o >> 7;
      const int slot = (o >> 4) & 7;
      gload_lds16(A + (size_t)(row0 + ridx) * 4096 + (tile << 6) + ((slot ^ (ridx & 7)) << 3),
                  (char*)&As[buf][0] + o);
    }
  };
  auto stageB = [&](int buf, int tile) {
#pragma unroll
    for (int g = 0; g < 3; ++g) {
      const int o = (g * 512 + t) * 16;
      const int ridx = o >> 7;
      const int slot = (o >> 4) & 7;
      gload_lds16(B + (size_t)(col0 + ridx) * 4096 + (tile << 6) + ((slot ^ (ridx & 7)) << 3),
                  (char*)&Bs[buf][0] + o);
    }
  };

  bf16x8 af[4][2], bfr[3][2];
  auto loadA = [&](int buf, int mh) {
#pragma unroll
    for (int f = 0; f < 4; ++f)
#pragma unroll
      for (int ks = 0; ks < 2; ++ks) {
        const int idx2 = wr * 128 + mh * 64 + f * 16 + l15;
        const int slot = ks * 4 + l4;
        af[f][ks] = *(const bf16x8*)((const char*)&As[buf][0] + idx2 * 128 +
                                     ((slot ^ (idx2 & 7)) << 4));
      }
  };
  auto loadB = [&](int buf) {
#pragma unroll
    for (int e = 0; e < 3; ++e)
#pragma unroll
      for (int ks = 0; ks < 2; ++ks) {
        const int idx2 = wc * 48 + e * 16 + l15;
        const int slot = ks * 4 + l4;
        bfr[e][ks] = *(const bf16x8*)((const char*)&Bs[buf][0] + idx2 * 128 +
                                      ((slot ^ (idx2 & 7)) << 4));
      }
  };

  f32x4 acc0[4][3], acc1[4][3];
#pragma unroll
  for (int f = 0; f < 4; ++f)
#pragma unroll
    for (int e = 0; e < 3; ++e) {
      acc0[f][e] = f32x4{0.f, 0.f, 0.f, 0.f};
      acc1[f][e] = f32x4{0.f, 0.f, 0.f, 0.f};
    }

  const int nkt = 4096 >> 6;

  stageA_part(0, 0, 0); stageA_part(0, 0, 1); stageB(0, 0);
  stageA_part(1, 1, 0); stageA_part(1, 1, 1); stageB(1, 1);
  VMW(7);
  BAR;

  for (int kt = 0; kt < nkt; ++kt) {
    const int buf = kt & 1;
    loadA(buf, 0); loadB(buf);
    if (kt >= 1 && kt + 1 < nkt) { stageA_part(buf ^ 1, kt + 1, 1); stageB(buf ^ 1, kt + 1); }
    BAR;
    PRIO1;
#pragma unroll
    for (int f = 0; f < 4; ++f)
#pragma unroll
      for (int e = 0; e < 3; ++e)
#pragma unroll
        for (int ks = 0; ks < 2; ++ks)
          acc0[f][e] = __builtin_amdgcn_mfma_f32_16x16x32_bf16(af[f][ks], bfr[e][ks], acc0[f][e],
                                                               0, 0, 0);
    PRIO0;
    BAR;
    loadA(buf, 1);
    if (kt + 2 < nkt) stageA_part(buf, kt + 2, 0);
    BAR;
    PRIO1;
#pragma unroll
    for (int f = 0; f < 4; ++f)
#pragma unroll
      for (int e = 0; e < 3; ++e)
#pragma unroll
        for (int ks = 0; ks < 2; ++ks)
          acc1[f][e] = __builtin_amdgcn_mfma_f32_16x16x32_bf16(af[f][ks], bfr[e][ks], acc1[f][e],
                                                               0, 0, 0);
    PRIO0;
    if (kt + 2 < nkt) { VMW(2); } else { VMW(0); }
    BAR;
  }

#pragma unroll
  for (int f = 0; f < 4; ++f)
#pragma unroll
    for (int e = 0; e < 3; ++e) {
      const int colb = col0 + wc * 48 + e * 16 + l15;
      const int r0a = row0 + wr * 128 + f * 16 + l4 * 4;
#pragma unroll
      for (int r = 0; r < 4; ++r)
        C[(size_t)(r0a + r) * NQKV + colb] = f2bf(acc0[f][e][r]);
      const int r0b = r0a + 64;
#pragma unroll
      for (int r = 0; r < 4; ++r)
        C[(size_t)(r0b + r) * NQKV + colb] = f2bf(acc1[f][e][r]);
    }
}

// ================= 8-phase GEMM, 16x16x32 MFMA, BM=128, BN=256 (Wo, f32 out) =================
// r12-verbatim (2 blocks/CU; measured faster than the BM=256/BN=128 2-phase variant).
template <int MH, int NH>
__device__ __forceinline__ void mfq16(f32x4 (&acc)[4][4], const bf16x8 (&af)[2][2],
                                      const bf16x8 (&b)[2][2]) {
#pragma unroll
  for (int f = 0; f < 2; ++f)
#pragma unroll
    for (int e = 0; e < 2; ++e)
#pragma unroll
      for (int ks = 0; ks < 2; ++ks)
        acc[MH * 2 + f][NH * 2 + e] = __builtin_amdgcn_mfma_f32_16x16x32_bf16(
            af[f][ks], b[e][ks], acc[MH * 2 + f][NH * 2 + e], 0, 0, 0);
}

__global__ void __launch_bounds__(512, 2) gemm8p16(
    const u16* __restrict__ A, const u16* __restrict__ B, float* __restrict__ C) {
  __shared__ u16 As[2][2][64 * 64];
  __shared__ u16 Bs[2][2][128 * 64];
  const int t = threadIdx.x;
  const int lane = t & 63, w = t >> 6;
  const int wr = w >> 2, wc = w & 3;
  const int l15 = lane & 15, l4 = lane >> 4;

  const int flat = blockIdx.x;
  const int xcd = flat & 7, idx = flat >> 3;
  const int bxt = idx & 15, byt = xcd * 2 + (idx >> 4);
  const int row0 = byt * 128, col0 = bxt * 256;

  auto stageA = [&](int buf, int half, int tile) {
    const int o = t * 16;
    const int ridx = o >> 7;
    const int slot = (o >> 4) & 7;
    const int gr = (ridx >> 5) * 64 + half * 32 + (ridx & 31);
    gload_lds16(A + (size_t)(row0 + gr) * 4096 + (tile << 6) + ((slot ^ (ridx & 7)) << 3),
                (char*)&As[buf][half][0] + o);
  };
  auto stageB = [&](int buf, int half, int tile) {
#pragma unroll
    for (int g = 0; g < 2; ++g) {
      const int o = (g * 512 + t) * 16;
      const int ridx = o >> 7;
      const int slot = (o >> 4) & 7;
      const int gn = (ridx >> 5) * 64 + half * 32 + (ridx & 31);
      gload_lds16(B + (size_t)(col0 + gn) * 4096 + (tile << 6) + ((slot ^ (ridx & 7)) << 3),
                  (char*)&Bs[buf][half][0] + o);
    }
  };

  bf16x8 af[2][2], bf0[2][2], bf1[2][2];
  auto loadA = [&](int buf, int half) {
#pragma unroll
    for (int f = 0; f < 2; ++f)
#pragma unroll
      for (int ks = 0; ks < 2; ++ks) {
        const int idx2 = wr * 32 + f * 16 + l15;
        const int slot = ks * 4 + l4;
        af[f][ks] = *(const bf16x8*)((const char*)&As[buf][half][0] + idx2 * 128 +
                                     ((slot ^ (idx2 & 7)) << 4));
      }
  };
  auto loadB = [&](int buf, int half, bf16x8 (&dst)[2][2]) {
#pragma unroll
    for (int e = 0; e < 2; ++e)
#pragma unroll
      for (int ks = 0; ks < 2; ++ks) {
        const int idx2 = wc * 32 + e * 16 + l15;
        const int slot = ks * 4 + l4;
        dst[e][ks] = *(const bf16x8*)((const char*)&Bs[buf][half][0] + idx2 * 128 +
                                      ((slot ^ (idx2 & 7)) << 4));
      }
  };

  f32x4 acc[4][4];
#pragma unroll
  for (int m_ = 0; m_ < 4; ++m_)
#pragma unroll
    for (int n_ = 0; n_ < 4; ++n_) acc[m_][n_] = f32x4{0.f, 0.f, 0.f, 0.f};

  const int nit = (4096 >> 6) >> 1;

  stageA(0, 0, 0); stageB(0, 0, 0); stageB(0, 1, 0); stageA(0, 1, 0);
  stageA(1, 0, 1); stageB(1, 0, 1); stageB(1, 1, 1); stageA(1, 1, 1);
  VMW(6);
  BAR;

  for (int i = 0; i < nit; ++i) {
    const int tb = 2 * i;
    const bool g2 = (i + 1 < nit);
    loadA(0, 0); loadB(0, 0, bf0);
    BAR; PRIO1; mfq16<0, 0>(acc, af, bf0); PRIO0; BAR;
    loadB(0, 1, bf1);
    if (g2) { stageA(0, 0, tb + 2); stageB(0, 0, tb + 2); }
    BAR; PRIO1; mfq16<0, 1>(acc, af, bf1); PRIO0; BAR;
    loadA(0, 1);
    if (g2) stageB(0, 1, tb + 2);
    BAR; PRIO1; mfq16<1, 1>(acc, af, bf1); PRIO0; BAR;
    if (g2) stageA(0, 1, tb + 2);
    BAR; PRIO1; mfq16<1, 0>(acc, af, bf0); PRIO0;
    if (g2) { VMW(6); } else { VMW(0); }
    BAR;
    loadA(1, 0); loadB(1, 0, bf0);
    BAR; PRIO1; mfq16<0, 0>(acc, af, bf0); PRIO0; BAR;
    loadB(1, 1, bf1);
    if (g2) { stageA(1, 0, tb + 3); stageB(1, 0, tb + 3); }
    BAR; PRIO1; mfq16<0, 1>(acc, af, bf1); PRIO0; BAR;
    loadA(1, 1);
    if (g2) stageB(1, 1, tb + 3);
    BAR; PRIO1; mfq16<1, 1>(acc, af, bf1); PRIO0; BAR;
    if (g2) stageA(1, 1, tb + 3);
    BAR; PRIO1; mfq16<1, 0>(acc, af, bf0); PRIO0;
    if (g2) { VMW(6); }
    BAR;
  }

#pragma unroll
  for (int am = 0; am < 4; ++am) {
    const int rowb = row0 + wr * 64 + (am >> 1) * 32 + (am & 1) * 16 + l4 * 4;
#pragma unroll
    for (int an = 0; an < 4; ++an) {
      const int colb = col0 + wc * 64 + (an >> 1) * 32 + (an & 1) * 16 + l15;
#pragma unroll
      for (int r = 0; r < 4; ++r)
        C[(size_t)(rowb + r) * 4096 + colb] = acc[am][an][r];
    }
  }
}

// ---------------- attention K staging (512 threads): K [64][128], swizzled ----------------
__device__ __forceinline__ void stage_k512(const u16* __restrict__ qkv, const int kvh,
                                           const int kv0, u16* KsB, const int t) {
#pragma unroll
  for (int i = 0; i < 2; ++i) {
    const int o = (i * 512 + t) * 16;
    const int row = o >> 8;
    const int slot = (o >> 4) & 15;
    gload_lds16(qkv + (size_t)(kv0 + row) * NQKV + 4096 + kvh * HD + ((slot ^ (row & 7)) << 3),
                (char*)KsB + o);
  }
}

// ---------------- causal GQA flash attention: QBLK=128, 8 waves, V direct from L2 ----------------
// LDS = 32KB (K dbuf only) -> up to 4 blocks/CU. V (512KB/kvh, L2-resident via kvh=xcd) read
// directly as B-frags: vt[(kvh*128+vrow)*2048 + kv0 + kb2*32 + l4*8] (un-swizzled r12 mapping).
__global__ void __launch_bounds__(512) attn_fwd(const u16* __restrict__ qkv,
                                                const u16* __restrict__ vt, u16* __restrict__ ctx) {
  __shared__ u16 Ks[2][64 * 128];
  const int t = threadIdx.x, lane = t & 63, w = t >> 6;
  const int bid = blockIdx.x;
  const int xcd = bid & 7, bi = bid >> 3;
  const int h = xcd * 4 + (bi & 3);
  const int j = bi >> 2;
  const int qbb = (j < 8) ? (15 - j) : (j - 8);  // balanced co-resident pairing
  const int kvh = xcd;
  const int q0 = qbb * 128;
  const int sq_base = q0 + w * 16;
  const int l15 = lane & 15, l4 = lane >> 4;
  const int sq_abs = sq_base + l15;
  const int bw = sq_base >> 6;

  bf16x8 qf[4];
  {
    const u16* qp = qkv + (size_t)sq_abs * NQKV + h * HD + l4 * 8;
#pragma unroll
    for (int kb = 0; kb < 4; ++kb) qf[kb] = *(const bf16x8*)(qp + kb * 32);
  }
  f32x4 po[8];
#pragma unroll
  for (int i = 0; i < 8; ++i) po[i] = f32x4{0.f, 0.f, 0.f, 0.f};
  float mrow = -1e30f;
  float lrow = 0.f;

  const int nb = 2 * qbb + 2;
  stage_k512(qkv, kvh, 0, Ks[0], t);
  __syncthreads();
  int cur = 0;

  for (int b = 0; b < nb; ++b) {
    if (b + 1 < nb) stage_k512(qkv, kvh, (b + 1) * 64, Ks[cur ^ 1], t);
    const int kv0 = b * 64;

    if (b <= bw) {
      f32x4 st[4];
#pragma unroll
      for (int c = 0; c < 4; ++c) st[c] = f32x4{0.f, 0.f, 0.f, 0.f};
#pragma unroll
      for (int c = 0; c < 4; ++c) {
        const int row = c * 16 + l15;
#pragma unroll
        for (int kb = 0; kb < 4; ++kb) {
          const int slot = kb * 4 + l4;
          bf16x8 bk = *(const bf16x8*)((const char*)Ks[cur] + row * 256 + ((slot ^ (row & 7)) << 4));
          st[c] = __builtin_amdgcn_mfma_f32_16x16x32_bf16(bk, qf[kb], st[c], 0, 0, 0);
        }
      }

      if (b == bw) {
#pragma unroll
        for (int c = 0; c < 4; ++c)
#pragma unroll
          for (int r = 0; r < 4; ++r) {
            const int sk = kv0 + c * 16 + l4 * 4 + r;
            if (sk > sq_abs) st[c][r] = -1e30f;
          }
      }

      float rmax = -3e38f;
#pragma unroll
      for (int c = 0; c < 4; ++c)
        rmax = fmaxf(rmax, fmaxf(fmaxf(st[c][0], st[c][1]), fmaxf(st[c][2], st[c][3])));
      rmax = fmaxf(rmax, __shfl_xor(rmax, 16, 64));
      rmax = fmaxf(rmax, __shfl_xor(rmax, 32, 64));

      const bool skip = __all(rmax <= mrow + 8.f);
      const float mnew = skip ? mrow : fmaxf(mrow, rmax);

      float rs = 0.f;
#pragma unroll
      for (int c = 0; c < 4; ++c) {
        const float e0 = exp2f(st[c][0] - mnew), e1 = exp2f(st[c][1] - mnew);
        const float e2 = exp2f(st[c][2] - mnew), e3 = exp2f(st[c][3] - mnew);
        st[c][0] = e0; st[c][1] = e1; st[c][2] = e2; st[c][3] = e3;
        rs += (e0 + e1) + (e2 + e3);
      }
      rs += __shfl_xor(rs, 16, 64);
      rs += __shfl_xor(rs, 32, 64);

      if (!skip) {
        const float alpha = exp2f(mrow - mnew);
        mrow = mnew;
        lrow = lrow * alpha + rs;
        float av[4];
#pragma unroll
        for (int r = 0; r < 4; ++r) av[r] = __shfl(alpha, l4 * 4 + r, 16);
#pragma unroll
        for (int db = 0; db < 8; ++db)
#pragma unroll
          for (int r = 0; r < 4; ++r) po[db][r] *= av[r];
      } else {
        lrow += rs;
      }

      u32 pk[4][2];
#pragma unroll
      for (int c = 0; c < 4; ++c) {
        pk[c][0] = (u32)f2bf(st[c][0]) | ((u32)f2bf(st[c][1]) << 16);
        pk[c][1] = (u32)f2bf(st[c][2]) | ((u32)f2bf(st[c][3]) << 16);
      }
      const int src01 = l15 + ((lane & 16) << 1);
      const int src23 = src01 + 16;
      const bool lo = (lane & 32) == 0;
#pragma unroll
      for (int kb2 = 0; kb2 < 2; ++kb2) {
        const int c0 = kb2 * 2, c1 = c0 + 1;
        const u32 a0 = (u32)__shfl((int)pk[c0][0], src01, 64);
        const u32 a1 = (u32)__shfl((int)pk[c0][1], src01, 64);
        const u32 a2 = (u32)__shfl((int)pk[c0][0], src23, 64);
        const u32 a3 = (u32)__shfl((int)pk[c0][1], src23, 64);
        const u32 b0 = (u32)__shfl((int)pk[c1][0], src01, 64);
        const u32 b1 = (u32)__shfl((int)pk[c1][1], src01, 64);
        const u32 b2 = (u32)__shfl((int)pk[c1][0], src23, 64);
        const u32 b3 = (u32)__shfl((int)pk[c1][1], src23, 64);
        u32x4 wq;
        wq.x = lo ? a0 : b0;
        wq.y = lo ? a1 : b1;
        wq.z = lo ? a2 : b2;
        wq.w = lo ? a3 : b3;
        const bf16x8 pa = __builtin_bit_cast(bf16x8, wq);
        const u16* vbase = vt + (size_t)(kvh * HD) * SEQ + kv0 + kb2 * 32 + l4 * 8;
#pragma unroll
        for (int db = 0; db < 8; ++db) {
          const int vrow = db * 16 + l15;
          bf16x8 bv = *(const bf16x8*)(vbase + (size_t)vrow * SEQ);
          po[db] = __builtin_amdgcn_mfma_f32_16x16x32_bf16(pa, bv, po[db], 0, 0, 0);
        }
      }
    }
    __syncthreads();
    cur ^= 1;
  }

  float rl[4];
#pragma unroll
  for (int r = 0; r < 4; ++r) rl[r] = 1.f / __shfl(lrow, l4 * 4 + r, 16);
#pragma unroll
  for (int db = 0; db < 8; ++db)
#pragma unroll
    for (int r = 0; r < 4; ++r) {
      const int sq = sq_base + l4 * 4 + r;
      const int d = db * 16 + l15;
      ctx[(size_t)sq * (NHEADS * HD) + h * HD + d] = f2bf(po[db][r] * rl[r]);
    }
}

extern "C" void kernel_launch(void* const* d_in, const int* in_sizes, int n_in,
                              void* d_out, int out_size, void* d_ws, size_t ws_size,
                              hipStream_t stream) {
  const float* hs = (const float*)d_in[0];
  const int* pos = (const int*)d_in[1];
  const float* Wq = (const float*)d_in[2];
  const float* Wk = (const float*)d_in[3];
  const float* Wv = (const float*)d_in[4];
  const float* Wo = (const float*)d_in[5];

  u16* ws = (u16*)d_ws;
  u16* Xb = ws;                                   // [2048][4096]
  u16* Wqt = Xb + (size_t)2048 * 4096;            // [6144][4096] contiguous (Wq^T|Wk^T|Wv^T)
  u16* Wkt = Wqt + (size_t)4096 * 4096;
  u16* Wvt = Wkt + (size_t)1024 * 4096;
  u16* Wot = Wvt + (size_t)1024 * 4096;           // [4096][4096]
  u16* qkvb = Wot + (size_t)4096 * 4096;          // [2048][6144]
  u16* vtb = qkvb + (size_t)2048 * 6144;          // [1024][2048]
  u16* ctx = vtb + (size_t)1024 * 2048;           // [2048][4096]
  const size_t need = ((size_t)(ctx - ws) + (size_t)2048 * 4096) * 2;
  if (ws_size < need) return;

  // fused X conversion + Wq/Wk/Wv transposes (-> contiguous B[6144][4096])
  prep_all<<<14336, 256, 0, stream>>>(hs, Xb, Wq, Wqt, Wk, Wkt, Wv, Wvt);

  // fused Q+K+V projection: single GEMM, 256 blocks (full CU fill), C = qkv [2048][6144]
  gemm_qkv<<<256, 512, 0, stream>>>(Xb, Wqt, qkvb);

  // fused RoPE(q) + RoPE(k) + V transpose + Wo transpose
  post_qkv<<<26624, 256, 0, stream>>>(qkvb, vtb, pos, Wo, Wot);

  // attention: 512 blocks, K staged in LDS (32KB), V direct from L2
  attn_fwd<<<512, 512, 0, stream>>>(qkvb, vtb, ctx);

  // output projection -> fp32 d_out (r12-verbatim gemm8p16)
  gemm8p16<<<256, 512, 0, stream>>>(ctx, Wot, (float*)d_out);
}

// Round 16
// 316.899 us; speedup vs baseline: 1.3682x; 1.3682x over previous
//
#include <hip/hip_runtime.h>
#include <hip/hip_bf16.h>
#include <math.h>

#define SEQ 2048
#define NHEADS 32
#define NKVH 8
#define HD 128
#define HIDDEN 4096
#define NQKV 6144

typedef unsigned short u16;
typedef unsigned int u32;
typedef __attribute__((ext_vector_type(8))) __bf16 bf16x8;
typedef __attribute__((ext_vector_type(4))) float f32x4;
typedef __attribute__((ext_vector_type(4))) u16 u16x4;
typedef __attribute__((ext_vector_type(4))) u32 u32x4;

__device__ __forceinline__ u16 f2bf(float f) {
  u32 u = __builtin_bit_cast(u32, f);
  u32 r = (u + 0x7fffu + ((u >> 16) & 1u)) >> 16;
  return (u16)r;
}
__device__ __forceinline__ float bf2f(u16 h) {
  return __builtin_bit_cast(float, ((u32)h) << 16);
}
__device__ __forceinline__ void gload_lds16(const void* g, void* l) {
  __builtin_amdgcn_global_load_lds(
      (const __attribute__((address_space(1))) u32*)g,
      (__attribute__((address_space(3))) u32*)l, 16, 0, 0);
}

#define BAR __builtin_amdgcn_s_barrier()
#define PRIO1 __builtin_amdgcn_s_setprio(1)
#define PRIO0 __builtin_amdgcn_s_setprio(0)
#define VMW(n) asm volatile("s_waitcnt vmcnt(" #n ")" ::: "memory")

// ---------------- vectorized 64x64 f32 -> bf16^T tile transpose ----------------
// float4 loads (16B/lane), u16x4 writes (8B/lane), LDS stride-65 (2-way free).
__device__ __forceinline__ void trans_tile64(const float* __restrict__ src, u16* __restrict__ dst,
                                             const int r0, const int c0, const int C, const int R,
                                             float (*tile)[65], const int t) {
  const int tx4 = t & 15, ty = t >> 4;
#pragma unroll
  for (int j = 0; j < 4; ++j) {
    const float4 v = *(const float4*)(src + (size_t)(r0 + ty + j * 16) * C + c0 + tx4 * 4);
    float* tp = &tile[ty + j * 16][tx4 * 4];
    tp[0] = v.x; tp[1] = v.y; tp[2] = v.z; tp[3] = v.w;
  }
  __syncthreads();
  const int rx4 = t & 15, cy = t >> 4;
#pragma unroll
  for (int j = 0; j < 4; ++j) {
    const int cc = cy + j * 16;
    u16x4 o;
    o.x = f2bf(tile[rx4 * 4 + 0][cc]);
    o.y = f2bf(tile[rx4 * 4 + 1][cc]);
    o.z = f2bf(tile[rx4 * 4 + 2][cc]);
    o.w = f2bf(tile[rx4 * 4 + 3][cc]);
    *(u16x4*)(dst + (size_t)(c0 + cc) * R + r0 + rx4 * 4) = o;
  }
}

// ---------------- fused prep: X f32->bf16 + Wq/Wk/Wv transpose f32->bf16^T ----------------
__global__ void __launch_bounds__(256) prep_all(
    const float* __restrict__ hs, u16* __restrict__ Xb,
    const float* __restrict__ Wq, u16* __restrict__ Wqt,
    const float* __restrict__ Wk, u16* __restrict__ Wkt,
    const float* __restrict__ Wv, u16* __restrict__ Wvt) {
  const int bid = blockIdx.x;
  if (bid < 8192) {  // X conversion, 4 f32/thread
    const int i = (bid * 256 + threadIdx.x) * 4;
    const float4 v = *(const float4*)(hs + i);
    u16x4 o;
    o.x = f2bf(v.x); o.y = f2bf(v.y); o.z = f2bf(v.z); o.w = f2bf(v.w);
    *(u16x4*)(Xb + i) = o;
    return;
  }
  __shared__ float tile[64][65];
  const float* src; u16* dst; int C, lc, tb;
  const int b2 = bid - 8192;
  if (b2 < 4096) { src = Wq; dst = Wqt; C = 4096; lc = 6; tb = b2; }
  else if (b2 < 5120) { src = Wk; dst = Wkt; C = 1024; lc = 4; tb = b2 - 4096; }
  else { src = Wv; dst = Wvt; C = 1024; lc = 4; tb = b2 - 5120; }
  const int r0 = (tb >> lc) * 64, c0 = (tb & ((1 << lc) - 1)) * 64;
  trans_tile64(src, dst, r0, c0, C, 4096, tile, threadIdx.x);
}

// ---------------- fused post-QKV: RoPE(q)+RoPE(k) + V transpose + Wo transpose ----------------
__global__ void __launch_bounds__(256) post_qkv(u16* __restrict__ qkv, u16* __restrict__ vtb,
                                                const int* __restrict__ pos,
                                                const float* __restrict__ Wsrc,
                                                u16* __restrict__ Wdst) {
  const int bid = blockIdx.x;
  if (bid < 20480) {  // RoPE
    int idx, hoff, sshift;
    float oscale;
    if (bid < 16384) {  // q: 32 heads at col 0
      idx = bid * 256 + threadIdx.x;
      hoff = ((idx >> 6) & 31) * 128;
      sshift = 11;
      oscale = 0.08838834764831845f * 1.44269504088896340f;  // 1/sqrt(128)*log2(e)
    } else {  // k: 8 heads at col 4096
      idx = (bid - 16384) * 256 + threadIdx.x;
      hoff = 4096 + ((idx >> 6) & 7) * 128;
      sshift = 9;
      oscale = 1.0f;
    }
    const int j = idx & 63;
    const int s = idx >> sshift;
    if (s >= SEQ) return;
    const float p = (float)pos[s];
    const float invf = __expf((float)j * -0.14391156831212787f);  // -ln(10000)/64
    const float ang = p * invf;
    const float c = cosf(ang), sn = sinf(ang);
    u16* bp = qkv + (size_t)s * NQKV + hoff + j;
    const float x1 = bf2f(bp[0]), x2 = bf2f(bp[64]);
    bp[0] = f2bf((x1 * c - x2 * sn) * oscale);
    bp[64] = f2bf((x2 * c + x1 * sn) * oscale);
    return;
  }
  if (bid < 22528) {
    // V transpose: qkv[:,5120:6144] ([2048][1024] strided) -> vtb [1024][2048]
    __shared__ u16 tile[32][34];
    const int b2 = bid - 20480;
    const int c0 = (b2 & 31) * 32, r0 = (b2 >> 5) * 32;
    const int tx = threadIdx.x & 31, ty = threadIdx.x >> 5;
#pragma unroll
    for (int i = 0; i < 4; ++i)
      tile[ty + i * 8][tx] = qkv[(size_t)(r0 + ty + i * 8) * NQKV + 5120 + c0 + tx];
    __syncthreads();
#pragma unroll
    for (int i = 0; i < 4; ++i)
      vtb[(size_t)(c0 + ty + i * 8) * 2048 + r0 + tx] = tile[tx][ty + i * 8];
    return;
  }
  // Wo transpose: f32 [4096][4096] -> bf16^T, one 64x64 tile per block (4096 blocks)
  __shared__ float tf[64][65];
  const int tb = bid - 22528;
  const int r0 = (tb >> 6) * 64, c0 = (tb & 63) * 64;
  trans_tile64(Wsrc, Wdst, r0, c0, 4096, 4096, tf, threadIdx.x);
}

// ================= QKV GEMM: BM=256, BN=192, BK=64, 256 blocks (full CU fill) =================
__global__ void __launch_bounds__(512) gemm_qkv(
    const u16* __restrict__ A, const u16* __restrict__ B, u16* __restrict__ C) {
  __shared__ u16 As[2][256 * 64];
  __shared__ u16 Bs[2][192 * 64];
  const int t = threadIdx.x;
  const int lane = t & 63, w = t >> 6;
  const int wr = w >> 2, wc = w & 3;
  const int l15 = lane & 15, l4 = lane >> 4;

  const int bid = blockIdx.x;
  const int xcd = bid & 7, ii = bid >> 3;
  const int byt = xcd, bxt = ii;
  const int row0 = byt * 256, col0 = bxt * 192;

  auto stageA_part = [&](int buf, int tile, int gfirst) {
#pragma unroll
    for (int gg = 0; gg < 2; ++gg) {
      const int g = gfirst + gg * 2;
      const int o = (g * 512 + t) * 16;
      const int ridx = o >> 7;
      const int slot = (o >> 4) & 7;
      gload_lds16(A + (size_t)(row0 + ridx) * 4096 + (tile << 6) + ((slot ^ (ridx & 7)) << 3),
                  (char*)&As[buf][0] + o);
    }
  };
  auto stageB = [&](int buf, int tile) {
#pragma unroll
    for (int g = 0; g < 3; ++g) {
      const int o = (g * 512 + t) * 16;
      const int ridx = o >> 7;
      const int slot = (o >> 4) & 7;
      gload_lds16(B + (size_t)(col0 + ridx) * 4096 + (tile << 6) + ((slot ^ (ridx & 7)) << 3),
                  (char*)&Bs[buf][0] + o);
    }
  };

  bf16x8 af[4][2], bfr[3][2];
  auto loadA = [&](int buf, int mh) {
#pragma unroll
    for (int f = 0; f < 4; ++f)
#pragma unroll
      for (int ks = 0; ks < 2; ++ks) {
        const int idx2 = wr * 128 + mh * 64 + f * 16 + l15;
        const int slot = ks * 4 + l4;
        af[f][ks] = *(const bf16x8*)((const char*)&As[buf][0] + idx2 * 128 +
                                     ((slot ^ (idx2 & 7)) << 4));
      }
  };
  auto loadB = [&](int buf) {
#pragma unroll
    for (int e = 0; e < 3; ++e)
#pragma unroll
      for (int ks = 0; ks < 2; ++ks) {
        const int idx2 = wc * 48 + e * 16 + l15;
        const int slot = ks * 4 + l4;
        bfr[e][ks] = *(const bf16x8*)((const char*)&Bs[buf][0] + idx2 * 128 +
                                      ((slot ^ (idx2 & 7)) << 4));
      }
  };

  f32x4 acc0[4][3], acc1[4][3];
#pragma unroll
  for (int f = 0; f < 4; ++f)
#pragma unroll
    for (int e = 0; e < 3; ++e) {
      acc0[f][e] = f32x4{0.f, 0.f, 0.f, 0.f};
      acc1[f][e] = f32x4{0.f, 0.f, 0.f, 0.f};
    }

  const int nkt = 4096 >> 6;

  stageA_part(0, 0, 0); stageA_part(0, 0, 1); stageB(0, 0);
  stageA_part(1, 1, 0); stageA_part(1, 1, 1); stageB(1, 1);
  VMW(7);
  BAR;

  for (int kt = 0; kt < nkt; ++kt) {
    const int buf = kt & 1;
    loadA(buf, 0); loadB(buf);
    if (kt >= 1 && kt + 1 < nkt) { stageA_part(buf ^ 1, kt + 1, 1); stageB(buf ^ 1, kt + 1); }
    BAR;
    PRIO1;
#pragma unroll
    for (int f = 0; f < 4; ++f)
#pragma unroll
      for (int e = 0; e < 3; ++e)
#pragma unroll
        for (int ks = 0; ks < 2; ++ks)
          acc0[f][e] = __builtin_amdgcn_mfma_f32_16x16x32_bf16(af[f][ks], bfr[e][ks], acc0[f][e],
                                                               0, 0, 0);
    PRIO0;
    BAR;
    loadA(buf, 1);
    if (kt + 2 < nkt) stageA_part(buf, kt + 2, 0);
    BAR;
    PRIO1;
#pragma unroll
    for (int f = 0; f < 4; ++f)
#pragma unroll
      for (int e = 0; e < 3; ++e)
#pragma unroll
        for (int ks = 0; ks < 2; ++ks)
          acc1[f][e] = __builtin_amdgcn_mfma_f32_16x16x32_bf16(af[f][ks], bfr[e][ks], acc1[f][e],
                                                               0, 0, 0);
    PRIO0;
    if (kt + 2 < nkt) { VMW(2); } else { VMW(0); }
    BAR;
  }

#pragma unroll
  for (int f = 0; f < 4; ++f)
#pragma unroll
    for (int e = 0; e < 3; ++e) {
      const int colb = col0 + wc * 48 + e * 16 + l15;
      const int r0a = row0 + wr * 128 + f * 16 + l4 * 4;
#pragma unroll
      for (int r = 0; r < 4; ++r)
        C[(size_t)(r0a + r) * NQKV + colb] = f2bf(acc0[f][e][r]);
      const int r0b = r0a + 64;
#pragma unroll
      for (int r = 0; r < 4; ++r)
        C[(size_t)(r0b + r) * NQKV + colb] = f2bf(acc1[f][e][r]);
    }
}

// ================= 8-phase GEMM, 16x16x32 MFMA, BM=128, BN=256 (Wo, f32 out) =================
template <int MH, int NH>
__device__ __forceinline__ void mfq16(f32x4 (&acc)[4][4], const bf16x8 (&af)[2][2],
                                      const bf16x8 (&b)[2][2]) {
#pragma unroll
  for (int f = 0; f < 2; ++f)
#pragma unroll
    for (int e = 0; e < 2; ++e)
#pragma unroll
      for (int ks = 0; ks < 2; ++ks)
        acc[MH * 2 + f][NH * 2 + e] = __builtin_amdgcn_mfma_f32_16x16x32_bf16(
            af[f][ks], b[e][ks], acc[MH * 2 + f][NH * 2 + e], 0, 0, 0);
}

__global__ void __launch_bounds__(512, 2) gemm8p16(
    const u16* __restrict__ A, const u16* __restrict__ B, float* __restrict__ C) {
  __shared__ u16 As[2][2][64 * 64];
  __shared__ u16 Bs[2][2][128 * 64];
  const int t = threadIdx.x;
  const int lane = t & 63, w = t >> 6;
  const int wr = w >> 2, wc = w & 3;
  const int l15 = lane & 15, l4 = lane >> 4;

  const int flat = blockIdx.x;
  const int xcd = flat & 7, idx = flat >> 3;
  const int bxt = idx & 15, byt = xcd * 2 + (idx >> 4);
  const int row0 = byt * 128, col0 = bxt * 256;

  auto stageA = [&](int buf, int half, int tile) {
    const int o = t * 16;
    const int ridx = o >> 7;
    const int slot = (o >> 4) & 7;
    const int gr = (ridx >> 5) * 64 + half * 32 + (ridx & 31);
    gload_lds16(A + (size_t)(row0 + gr) * 4096 + (tile << 6) + ((slot ^ (ridx & 7)) << 3),
                (char*)&As[buf][half][0] + o);
  };
  auto stageB = [&](int buf, int half, int tile) {
#pragma unroll
    for (int g = 0; g < 2; ++g) {
      const int o = (g * 512 + t) * 16;
      const int ridx = o >> 7;
      const int slot = (o >> 4) & 7;
      const int gn = (ridx >> 5) * 64 + half * 32 + (ridx & 31);
      gload_lds16(B + (size_t)(col0 + gn) * 4096 + (tile << 6) + ((slot ^ (ridx & 7)) << 3),
                  (char*)&Bs[buf][half][0] + o);
    }
  };

  bf16x8 af[2][2], bf0[2][2], bf1[2][2];
  auto loadA = [&](int buf, int half) {
#pragma unroll
    for (int f = 0; f < 2; ++f)
#pragma unroll
      for (int ks = 0; ks < 2; ++ks) {
        const int idx2 = wr * 32 + f * 16 + l15;
        const int slot = ks * 4 + l4;
        af[f][ks] = *(const bf16x8*)((const char*)&As[buf][half][0] + idx2 * 128 +
                                     ((slot ^ (idx2 & 7)) << 4));
      }
  };
  auto loadB = [&](int buf, int half, bf16x8 (&dst)[2][2]) {
#pragma unroll
    for (int e = 0; e < 2; ++e)
#pragma unroll
      for (int ks = 0; ks < 2; ++ks) {
        const int idx2 = wc * 32 + e * 16 + l15;
        const int slot = ks * 4 + l4;
        dst[e][ks] = *(const bf16x8*)((const char*)&Bs[buf][half][0] + idx2 * 128 +
                                      ((slot ^ (idx2 & 7)) << 4));
      }
  };

  f32x4 acc[4][4];
#pragma unroll
  for (int m_ = 0; m_ < 4; ++m_)
#pragma unroll
    for (int n_ = 0; n_ < 4; ++n_) acc[m_][n_] = f32x4{0.f, 0.f, 0.f, 0.f};

  const int nit = (4096 >> 6) >> 1;

  stageA(0, 0, 0); stageB(0, 0, 0); stageB(0, 1, 0); stageA(0, 1, 0);
  stageA(1, 0, 1); stageB(1, 0, 1); stageB(1, 1, 1); stageA(1, 1, 1);
  VMW(6);
  BAR;

  for (int i = 0; i < nit; ++i) {
    const int tb = 2 * i;
    const bool g2 = (i + 1 < nit);
    loadA(0, 0); loadB(0, 0, bf0);
    BAR; PRIO1; mfq16<0, 0>(acc, af, bf0); PRIO0; BAR;
    loadB(0, 1, bf1);
    if (g2) { stageA(0, 0, tb + 2); stageB(0, 0, tb + 2); }
    BAR; PRIO1; mfq16<0, 1>(acc, af, bf1); PRIO0; BAR;
    loadA(0, 1);
    if (g2) stageB(0, 1, tb + 2);
    BAR; PRIO1; mfq16<1, 1>(acc, af, bf1); PRIO0; BAR;
    if (g2) stageA(0, 1, tb + 2);
    BAR; PRIO1; mfq16<1, 0>(acc, af, bf0); PRIO0;
    if (g2) { VMW(6); } else { VMW(0); }
    BAR;
    loadA(1, 0); loadB(1, 0, bf0);
    BAR; PRIO1; mfq16<0, 0>(acc, af, bf0); PRIO0; BAR;
    loadB(1, 1, bf1);
    if (g2) { stageA(1, 0, tb + 3); stageB(1, 0, tb + 3); }
    BAR; PRIO1; mfq16<0, 1>(acc, af, bf1); PRIO0; BAR;
    loadA(1, 1);
    if (g2) stageB(1, 1, tb + 3);
    BAR; PRIO1; mfq16<1, 1>(acc, af, bf1); PRIO0; BAR;
    if (g2) stageA(1, 1, tb + 3);
    BAR; PRIO1; mfq16<1, 0>(acc, af, bf0); PRIO0;
    if (g2) { VMW(6); }
    BAR;
  }

#pragma unroll
  for (int am = 0; am < 4; ++am) {
    const int rowb = row0 + wr * 64 + (am >> 1) * 32 + (am & 1) * 16 + l4 * 4;
#pragma unroll
    for (int an = 0; an < 4; ++an) {
      const int colb = col0 + wc * 64 + (an >> 1) * 32 + (an & 1) * 16 + l15;
#pragma unroll
      for (int r = 0; r < 4; ++r)
        C[(size_t)(rowb + r) * 4096 + colb] = acc[am][an][r];
    }
  }
}

// ---------------- attention staging (512 threads): K [64][128] + V^T [128][64], swizzled ----------------
__device__ __forceinline__ void stage_kv512(const u16* __restrict__ qkv, const u16* __restrict__ vt,
                                            const int kvh, const int kv0, u16* KsB, u16* VsB,
                                            const int t) {
#pragma unroll
  for (int i = 0; i < 2; ++i) {
    const int o = (i * 512 + t) * 16;
    const int row = o >> 8;
    const int slot = (o >> 4) & 15;
    gload_lds16(qkv + (size_t)(kv0 + row) * NQKV + 4096 + kvh * HD + ((slot ^ (row & 7)) << 3),
                (char*)KsB + o);
  }
#pragma unroll
  for (int i = 0; i < 2; ++i) {
    const int o = (i * 512 + t) * 16;
    const int row = o >> 7;
    const int slot = (o >> 4) & 7;
    gload_lds16(vt + (size_t)(kvh * HD + row) * SEQ + kv0 + ((slot ^ (row & 7)) << 3),
                (char*)VsB + o);
  }
}

// ---------------- causal GQA flash attention: QBLK=128, 8 waves, balanced pairing (r12) ----------------
__global__ void __launch_bounds__(512) attn_fwd(const u16* __restrict__ qkv,
                                                const u16* __restrict__ vt, u16* __restrict__ ctx) {
  __shared__ u16 Ks[2][64 * 128];
  __shared__ u16 Vs[2][128 * 64];
  const int t = threadIdx.x, lane = t & 63, w = t >> 6;
  const int bid = blockIdx.x;
  const int xcd = bid & 7, bi = bid >> 3;
  const int h = xcd * 4 + (bi & 3);
  const int j = bi >> 2;
  const int qbb = (j < 8) ? (15 - j) : (j - 8);
  const int kvh = xcd;
  const int q0 = qbb * 128;
  const int sq_base = q0 + w * 16;
  const int l15 = lane & 15, l4 = lane >> 4;
  const int sq_abs = sq_base + l15;
  const int bw = sq_base >> 6;

  bf16x8 qf[4];
  {
    const u16* qp = qkv + (size_t)sq_abs * NQKV + h * HD + l4 * 8;
#pragma unroll
    for (int kb = 0; kb < 4; ++kb) qf[kb] = *(const bf16x8*)(qp + kb * 32);
  }
  f32x4 po[8];
#pragma unroll
  for (int i = 0; i < 8; ++i) po[i] = f32x4{0.f, 0.f, 0.f, 0.f};
  float mrow = -1e30f;
  float lrow = 0.f;

  const int nb = 2 * qbb + 2;
  stage_kv512(qkv, vt, kvh, 0, Ks[0], Vs[0], t);
  __syncthreads();
  int cur = 0;

  for (int b = 0; b < nb; ++b) {
    if (b + 1 < nb) stage_kv512(qkv, vt, kvh, (b + 1) * 64, Ks[cur ^ 1], Vs[cur ^ 1], t);

    if (b <= bw) {
      f32x4 st[4];
#pragma unroll
      for (int c = 0; c < 4; ++c) st[c] = f32x4{0.f, 0.f, 0.f, 0.f};
#pragma unroll
      for (int c = 0; c < 4; ++c) {
        const int row = c * 16 + l15;
#pragma unroll
        for (int kb = 0; kb < 4; ++kb) {
          const int slot = kb * 4 + l4;
          bf16x8 bk = *(const bf16x8*)((const char*)Ks[cur] + row * 256 + ((slot ^ (row & 7)) << 4));
          st[c] = __builtin_amdgcn_mfma_f32_16x16x32_bf16(bk, qf[kb], st[c], 0, 0, 0);
        }
      }

      if (b == bw) {
#pragma unroll
        for (int c = 0; c < 4; ++c)
#pragma unroll
          for (int r = 0; r < 4; ++r) {
            const int sk = b * 64 + c * 16 + l4 * 4 + r;
            if (sk > sq_abs) st[c][r] = -1e30f;
          }
      }

      float rmax = -3e38f;
#pragma unroll
      for (int c = 0; c < 4; ++c)
        rmax = fmaxf(rmax, fmaxf(fmaxf(st[c][0], st[c][1]), fmaxf(st[c][2], st[c][3])));
      rmax = fmaxf(rmax, __shfl_xor(rmax, 16, 64));
      rmax = fmaxf(rmax, __shfl_xor(rmax, 32, 64));

      const bool skip = __all(rmax <= mrow + 8.f);
      const float mnew = skip ? mrow : fmaxf(mrow, rmax);

      float rs = 0.f;
#pragma unroll
      for (int c = 0; c < 4; ++c) {
        const float e0 = exp2f(st[c][0] - mnew), e1 = exp2f(st[c][1] - mnew);
        const float e2 = exp2f(st[c][2] - mnew), e3 = exp2f(st[c][3] - mnew);
        st[c][0] = e0; st[c][1] = e1; st[c][2] = e2; st[c][3] = e3;
        rs += (e0 + e1) + (e2 + e3);
      }
      rs += __shfl_xor(rs, 16, 64);
      rs += __shfl_xor(rs, 32, 64);

      if (!skip) {
        const float alpha = exp2f(mrow - mnew);
        mrow = mnew;
        lrow = lrow * alpha + rs;
        float av[4];
#pragma unroll
        for (int r = 0; r < 4; ++r) av[r] = __shfl(alpha, l4 * 4 + r, 16);
#pragma unroll
        for (int db = 0; db < 8; ++db)
#pragma unroll
          for (int r = 0; r < 4; ++r) po[db][r] *= av[r];
      } else {
        lrow += rs;
      }

      u32 pk[4][2];
#pragma unroll
      for (int c = 0; c < 4; ++c) {
        pk[c][0] = (u32)f2bf(st[c][0]) | ((u32)f2bf(st[c][1]) << 16);
        pk[c][1] = (u32)f2bf(st[c][2]) | ((u32)f2bf(st[c][3]) << 16);
      }
      const int src01 = l15 + ((lane & 16) << 1);
      const int src23 = src01 + 16;
      const bool lo = (lane & 32) == 0;
#pragma unroll
      for (int kb2 = 0; kb2 < 2; ++kb2) {
        const int c0 = kb2 * 2, c1 = c0 + 1;
        const u32 a0 = (u32)__shfl((int)pk[c0][0], src01, 64);
        const u32 a1 = (u32)__shfl((int)pk[c0][1], src01, 64);
        const u32 a2 = (u32)__shfl((int)pk[c0][0], src23, 64);
        const u32 a3 = (u32)__shfl((int)pk[c0][1], src23, 64);
        const u32 b0 = (u32)__shfl((int)pk[c1][0], src01, 64);
        const u32 b1 = (u32)__shfl((int)pk[c1][1], src01, 64);
        const u32 b2 = (u32)__shfl((int)pk[c1][0], src23, 64);
        const u32 b3 = (u32)__shfl((int)pk[c1][1], src23, 64);
        u32x4 wq;
        wq.x = lo ? a0 : b0;
        wq.y = lo ? a1 : b1;
        wq.z = lo ? a2 : b2;
        wq.w = lo ? a3 : b3;
        const bf16x8 pa = __builtin_bit_cast(bf16x8, wq);
#pragma unroll
        for (int db = 0; db < 8; ++db) {
          const int vrow = db * 16 + l15;
          const int pslot = kb2 * 4 + l4;
          bf16x8 bv =
              *(const bf16x8*)((const char*)Vs[cur] + vrow * 128 + ((pslot ^ (vrow & 7)) << 4));
          po[db] = __builtin_amdgcn_mfma_f32_16x16x32_bf16(pa, bv, po[db], 0, 0, 0);
        }
      }
    }
    __syncthreads();
    cur ^= 1;
  }

  float rl[4];
#pragma unroll
  for (int r = 0; r < 4; ++r) rl[r] = 1.f / __shfl(lrow, l4 * 4 + r, 16);
#pragma unroll
  for (int db = 0; db < 8; ++db)
#pragma unroll
    for (int r = 0; r < 4; ++r) {
      const int sq = sq_base + l4 * 4 + r;
      const int d = db * 16 + l15;
      ctx[(size_t)sq * (NHEADS * HD) + h * HD + d] = f2bf(po[db][r] * rl[r]);
    }
}

extern "C" void kernel_launch(void* const* d_in, const int* in_sizes, int n_in,
                              void* d_out, int out_size, void* d_ws, size_t ws_size,
                              hipStream_t stream) {
  const float* hs = (const float*)d_in[0];
  const int* pos = (const int*)d_in[1];
  const float* Wq = (const float*)d_in[2];
  const float* Wk = (const float*)d_in[3];
  const float* Wv = (const float*)d_in[4];
  const float* Wo = (const float*)d_in[5];

  u16* ws = (u16*)d_ws;
  u16* Xb = ws;                                   // [2048][4096]
  u16* Wqt = Xb + (size_t)2048 * 4096;            // [6144][4096] contiguous (Wq^T|Wk^T|Wv^T)
  u16* Wkt = Wqt + (size_t)4096 * 4096;
  u16* Wvt = Wkt + (size_t)1024 * 4096;
  u16* Wot = Wvt + (size_t)1024 * 4096;           // [4096][4096]
  u16* qkvb = Wot + (size_t)4096 * 4096;          // [2048][6144]
  u16* vtb = qkvb + (size_t)2048 * 6144;          // [1024][2048]
  u16* ctx = vtb + (size_t)1024 * 2048;           // [2048][4096]
  const size_t need = ((size_t)(ctx - ws) + (size_t)2048 * 4096) * 2;
  if (ws_size < need) return;

  // fused X conversion + Wq/Wk/Wv transposes (vectorized f32x4/u16x4)
  prep_all<<<14336, 256, 0, stream>>>(hs, Xb, Wq, Wqt, Wk, Wkt, Wv, Wvt);

  // fused Q+K+V projection: single GEMM, 256 blocks (full CU fill), C = qkv [2048][6144]
  gemm_qkv<<<256, 512, 0, stream>>>(Xb, Wqt, qkvb);

  // fused RoPE(q) + RoPE(k) + V transpose + Wo transpose (vectorized)
  post_qkv<<<26624, 256, 0, stream>>>(qkvb, vtb, pos, Wo, Wot);

  // attention: 512 blocks, all co-resident, balanced qbb pairing (r12-verbatim)
  attn_fwd<<<512, 512, 0, stream>>>(qkvb, vtb, ctx);

  // output projection -> fp32 d_out (r12-verbatim gemm8p16)
  gemm8p16<<<256, 512, 0, stream>>>(ctx, Wot, (float*)d_out);
}